// Round 20
// baseline (49.909 us; speedup 1.0000x reference)
//
#include <hip/hip_runtime.h>
#include <math.h>

// V=4 views, N=8192 points, 6 directed chamfer terms (pair p rows=view pi, min over view pj)
#define VNUM   4
#define NPAIRS 6
#define BLK    256
#define QTILE  2048   // b-points per block (quarter of N)
#define CHUNK  1024   // b-points staged per LDS phase (32 KB)

using short8  = __attribute__((ext_vector_type(8)))  short;
using f32x16  = __attribute__((ext_vector_type(16))) float;

__device__ inline unsigned short f2bf(float x) {           // RNE to bf16
    unsigned u = __float_as_uint(x);
    return (unsigned short)((u + 0x7FFFu + ((u >> 16) & 1u)) >> 16);
}
__device__ inline float bf2f(unsigned short b) {
    return __uint_as_float(((unsigned)b) << 16);
}
__device__ inline unsigned pk(unsigned short lo, unsigned short hi) {
    return (unsigned)lo | ((unsigned)hi << 16);
}

// Kernel 1: world-transform, build K=16 bf16 fragments so that
// dot(Afrag[a], Bfrag[b]) = |a|^2 + |b|^2 - 2*(a_hi+a_lo).(b_hi+b_lo).
__global__ void setup_kernel(const float* __restrict__ pts,
                             const float* __restrict__ poses,
                             unsigned short* __restrict__ afr,
                             unsigned short* __restrict__ bfr,
                             unsigned int* __restrict__ minbuf,
                             float* __restrict__ out, int N) {
    int idx = blockIdx.x * blockDim.x + threadIdx.x;
    if (idx < NPAIRS * N) minbuf[idx] = 0x7F7FFFFFu;       // FLT_MAX bits
    if (idx == 0) *out = 0.0f;
    if (idx < VNUM * N) {
        int v = idx / N;
        const float* P = poses + v * 16;                   // row-major 4x4
        float px = pts[idx*3+0], py = pts[idx*3+1], pz = pts[idx*3+2];
        float x = fmaf(P[0], px, fmaf(P[1], py, fmaf(P[2],  pz, P[3])));
        float y = fmaf(P[4], px, fmaf(P[5], py, fmaf(P[6],  pz, P[7])));
        float z = fmaf(P[8], px, fmaf(P[9], py, fmaf(P[10], pz, P[11])));
        float s = fmaf(x, x, fmaf(y, y, z * z));
        unsigned short xh = f2bf(x), yh = f2bf(y), zh = f2bf(z);
        unsigned short xl = f2bf(x - bf2f(xh));
        unsigned short yl = f2bf(y - bf2f(yh));
        unsigned short zl = f2bf(z - bf2f(zh));
        unsigned short sh = f2bf(s), sl = f2bf(s - bf2f(sh));
        const unsigned short one = 0x3F80u;
        // -2 * bf16 is exact (power-of-two scale)
        unsigned short bxh = f2bf(-2.0f * bf2f(xh)), byh = f2bf(-2.0f * bf2f(yh)),
                       bzh = f2bf(-2.0f * bf2f(zh));
        unsigned short bxl = f2bf(-2.0f * bf2f(xl)), byl = f2bf(-2.0f * bf2f(yl)),
                       bzl = f2bf(-2.0f * bf2f(zl));
        // A[0..15] = xh,yh,zh, xh,yh,zh, xl,yl,zl, sh,sl, one,one, xl,yl,zl
        uint4* A4 = (uint4*)(afr + (size_t)idx * 16);
        A4[0] = make_uint4(pk(xh,yh), pk(zh,xh), pk(yh,zh), pk(xl,yl));
        A4[1] = make_uint4(pk(zl,sh), pk(sl,one), pk(one,xl), pk(yl,zl));
        // B[0..15] = bxh,byh,bzh, bxl,byl,bzl, bxh,byh,bzh, one,one, sh,sl, bxl,byl,bzl
        uint4* B4 = (uint4*)(bfr + (size_t)idx * 16);
        B4[0] = make_uint4(pk(bxh,byh), pk(bzh,bxl), pk(byl,bzl), pk(bxh,byh));
        B4[1] = make_uint4(pk(bzh,one), pk(one,sh), pk(sl,bxl), pk(byl,bzl));
    }
}

// Kernel 2: R19 chamfer, byte-identical. (Launched TWICE this round as a
// timing decomposition probe -- atomicMin combine is idempotent, so the
// second dispatch recomputes identical mins and output is unchanged.)
__global__ __launch_bounds__(BLK, 4)
void chamfer_kernel(const unsigned short* __restrict__ afr,
                    const unsigned short* __restrict__ bfr,
                    unsigned int* __restrict__ minbuf, int N) {
    __shared__ short8 sbuf[CHUNK * 2];            // 32 KB: [hi x1024][lo x1024]
    const int p  = blockIdx.z;
    const int pi = (p < 3) ? 0 : ((p < 5) ? 1 : 2);
    const int pj = (p < 3) ? (p + 1) : ((p < 5) ? (p - 1) : 3);
    const int tid  = threadIdx.x;
    const int w    = tid >> 6;
    const int l    = tid & 63;
    const int col  = l & 31;
    const int half = l >> 5;

    const int abase = (blockIdx.y * 4 + w) * 64;  // 64 a-rows per wave
    const int b0    = blockIdx.x * QTILE;

    const short8* aptr =
        (const short8*)(afr + ((size_t)pi * N + abase + col) * 16 + half * 8);
    const short8 A0 = aptr[0];
    const short8 A1 = aptr[64];                   // +32 points

    const char* gq = (const char*)(bfr + ((size_t)pj * N + b0) * 16);

    f32x16 m0, m1, zz;
#pragma unroll
    for (int i = 0; i < 16; ++i) { m0[i] = 3.402823466e38f; m1[i] = 3.402823466e38f; zz[i] = 0.0f; }

    for (int c = 0; c < QTILE / CHUNK; ++c) {
        __syncthreads();                          // previous phase fully consumed
        const char* gc = gq + (size_t)c * CHUNK * 32;
#pragma unroll
        for (int it = 0; it < (CHUNK * 32) / (BLK * 16); ++it) {   // 8 iters
            int i = it * BLK + tid;               // 0..2047 linear LDS slot
            const char* src = (i < CHUNK) ? (gc + (size_t)i * 32)
                                          : (gc + (size_t)(i - CHUNK) * 32 + 16);
            __builtin_amdgcn_global_load_lds(
                (const __attribute__((address_space(1))) unsigned int*)src,
                (__attribute__((address_space(3))) unsigned int*)(sbuf + i),
                16, 0, 0);
        }
        __syncthreads();                          // drains vmcnt, data visible

        const short8* bsel = half ? (sbuf + CHUNK) : sbuf;
        for (int t = 0; t < CHUNK / 32; t += 2) { // 2 b-tiles per iteration
            short8 B0 = bsel[t * 32 + col];
            short8 B1 = bsel[(t + 1) * 32 + col];
            f32x16 d0 = __builtin_amdgcn_mfma_f32_32x32x16_bf16(A0, B0, zz, 0, 0, 0);
            f32x16 d1 = __builtin_amdgcn_mfma_f32_32x32x16_bf16(A0, B1, zz, 0, 0, 0);
#pragma unroll
            for (int i = 0; i < 16; ++i)          // fminf only -> v_min3 fusion
                m0[i] = fminf(m0[i], fminf(d0[i], d1[i]));
            d0 = __builtin_amdgcn_mfma_f32_32x32x16_bf16(A1, B0, zz, 0, 0, 0);
            d1 = __builtin_amdgcn_mfma_f32_32x32x16_bf16(A1, B1, zz, 0, 0, 0);
#pragma unroll
            for (int i = 0; i < 16; ++i)
                m1[i] = fminf(m1[i], fminf(d0[i], d1[i]));
        }
    }

    // ---- epilogue: butterfly min across the 32 lanes of each half ----
#pragma unroll
    for (int off = 1; off <= 16; off <<= 1) {
#pragma unroll
        for (int i = 0; i < 16; ++i) {
            m0[i] = fminf(m0[i], __shfl_xor(m0[i], off, 64));
            m1[i] = fminf(m1[i], __shfl_xor(m1[i], off, 64));
        }
    }
    if (col == 0) {
        unsigned int* mb = minbuf + (size_t)p * N;
#pragma unroll
        for (int r = 0; r < 16; ++r) {
            int row = (r & 3) + 8 * (r >> 2) + 4 * half;   // verified C/D mapping
            atomicMin(&mb[abase + row],
                      __float_as_uint(fmaxf(m0[r], 0.0f)));
            atomicMin(&mb[abase + 32 + row],
                      __float_as_uint(fmaxf(m1[r], 0.0f)));
        }
    }
}

// Kernel 3: d = sqrt(min d^2), block-reduce, scaled atomicAdd into scalar out.
__global__ void finalize_kernel(const unsigned int* __restrict__ minbuf,
                                float* __restrict__ out, float scale) {
    __shared__ float red[BLK / 64];
    int idx = blockIdx.x * blockDim.x + threadIdx.x;
    float d = sqrtf(__uint_as_float(minbuf[idx]));
#pragma unroll
    for (int off = 32; off >= 1; off >>= 1)
        d += __shfl_down(d, off, 64);
    int lane = threadIdx.x & 63;
    int wid  = threadIdx.x >> 6;
    if (lane == 0) red[wid] = d;
    __syncthreads();
    if (threadIdx.x == 0) {
        float s = 0.0f;
#pragma unroll
        for (int wv = 0; wv < BLK / 64; ++wv) s += red[wv];
        atomicAdd(out, s * scale);
    }
}

extern "C" void kernel_launch(void* const* d_in, const int* in_sizes, int n_in,
                              void* d_out, int out_size, void* d_ws, size_t ws_size,
                              hipStream_t stream) {
    const float* points = (const float*)d_in[0];   // V x N x 3 fp32
    const float* poses  = (const float*)d_in[1];   // V x 4 x 4 fp32
    float* out = (float*)d_out;                    // scalar fp32

    const int N = in_sizes[0] / (VNUM * 3);        // 8192

    // ws: afr (V*N*16 bf16 = 1MB) | bfr (1MB) | minbuf (6*N uint = 192KB)
    unsigned short* afr = (unsigned short*)d_ws;
    unsigned short* bfr = afr + (size_t)VNUM * N * 16;
    unsigned int* minbuf = (unsigned int*)(bfr + (size_t)VNUM * N * 16);

    int setup_threads = NPAIRS * N;
    setup_kernel<<<(setup_threads + BLK - 1) / BLK, BLK, 0, stream>>>(
        points, poses, afr, bfr, minbuf, out, N);

    dim3 grid(N / QTILE, N / 256, NPAIRS);         // 4 x 32 x 6 = 768 blocks
    // DIAGNOSTIC: two identical dispatches (idempotent atomicMin) -- the
    // marginal time of the second = true chamfer kernel duration + 1 gap.
    chamfer_kernel<<<grid, BLK, 0, stream>>>(afr, bfr, minbuf, N);
    chamfer_kernel<<<grid, BLK, 0, stream>>>(afr, bfr, minbuf, N);

    finalize_kernel<<<(NPAIRS * N) / BLK, BLK, 0, stream>>>(
        minbuf, out, 1.0f / (6.0f * (float)N));
}

// Round 21
// 29.109 us; speedup vs baseline: 1.7146x; 1.7146x over previous
//
#include <hip/hip_runtime.h>
#include <math.h>

// V=4 views, N=8192 points, 6 directed chamfer terms (pair p rows=view pi, min over view pj)
#define VNUM   4
#define NPAIRS 6
#define BLK    256
#define QTILE  2048   // b-points per block (quarter of N)
#define CHUNK  1024   // b-points staged per LDS phase (32 KB)

using short8  = __attribute__((ext_vector_type(8)))  short;
using f32x16  = __attribute__((ext_vector_type(16))) float;

__device__ inline unsigned short f2bf(float x) {           // RNE to bf16
    unsigned u = __float_as_uint(x);
    return (unsigned short)((u + 0x7FFFu + ((u >> 16) & 1u)) >> 16);
}
__device__ inline float bf2f(unsigned short b) {
    return __uint_as_float(((unsigned)b) << 16);
}

// world-transform + hi/lo bf16 split (s = |p|^2) -- verified in R7
__device__ inline void xform_split(const float* __restrict__ P,
                                   float px, float py, float pz,
                                   unsigned short& xh, unsigned short& xl,
                                   unsigned short& yh, unsigned short& yl,
                                   unsigned short& zh, unsigned short& zl,
                                   unsigned short& sh, unsigned short& sl) {
    float x = fmaf(P[0], px, fmaf(P[1], py, fmaf(P[2],  pz, P[3])));
    float y = fmaf(P[4], px, fmaf(P[5], py, fmaf(P[6],  pz, P[7])));
    float z = fmaf(P[8], px, fmaf(P[9], py, fmaf(P[10], pz, P[11])));
    float s = fmaf(x, x, fmaf(y, y, z * z));
    xh = f2bf(x); xl = f2bf(x - bf2f(xh));
    yh = f2bf(y); yl = f2bf(y - bf2f(yh));
    zh = f2bf(z); zl = f2bf(z - bf2f(zh));
    sh = f2bf(s); sl = f2bf(s - bf2f(sh));
}

// Kernel 1 (of 2): fused fragment-build + chamfer. A-frags built in
// registers (R7-verified math: dot(A,B) = |a|^2+|b|^2-2(a_hi+a_lo).(b_hi+b_lo));
// B-frags transformed per 1024-pt chunk into LDS ([hi x1024][lo x1024]).
// Inner MFMA loop byte-identical to R19. Epilogue: plain per-x-block stores
// (minbuf[p][bx][row], NO init needed, NO atomics). Block (0,0,0) zeroes out.
// NO finalize tail here (R15/R18: any coherence tail collapses regalloc).
__global__ __launch_bounds__(BLK, 4)
void chamfer_kernel(const float* __restrict__ pts,
                    const float* __restrict__ poses,
                    float* __restrict__ minbuf,
                    float* __restrict__ out, int N) {
    __shared__ short8 sbuf[CHUNK * 2];            // 32 KB: [hi x1024][lo x1024]
    const int p  = blockIdx.z;
    const int pi = (p < 3) ? 0 : ((p < 5) ? 1 : 2);
    const int pj = (p < 3) ? (p + 1) : ((p < 5) ? (p - 1) : 3);
    const int tid  = threadIdx.x;
    const int w    = tid >> 6;
    const int l    = tid & 63;
    const int col  = l & 31;
    const int half = l >> 5;

    const int abase = (blockIdx.y * 4 + w) * 64;  // 64 a-rows per wave
    const int b0    = blockIdx.x * QTILE;
    const float* Pi = poses + pi * 16;
    const float* Pj = poses + pj * 16;
    const short one = (short)0x3F80;

    if (blockIdx.x == 0 && blockIdx.y == 0 && p == 0 && tid == 0)
        *out = 0.0f;                              // finalize runs strictly after

    // ---- A-fragments for this lane's two a-points (R7-verified) ----
    short8 A0, A1;
#pragma unroll
    for (int q = 0; q < 2; ++q) {
        int r = pi * N + abase + col + q * 32;
        unsigned short xh, xl, yh, yl, zh, zl, sh, sl;
        xform_split(Pi, pts[r*3], pts[r*3+1], pts[r*3+2],
                    xh, xl, yh, yl, zh, zl, sh, sl);
        short8 e07, e8f;
        e07[0]=(short)xh; e07[1]=(short)yh; e07[2]=(short)zh; e07[3]=(short)xh;
        e07[4]=(short)yh; e07[5]=(short)zh; e07[6]=(short)xl; e07[7]=(short)yl;
        e8f[0]=(short)zl; e8f[1]=(short)sh; e8f[2]=(short)sl; e8f[3]=one;
        e8f[4]=one;       e8f[5]=(short)xl; e8f[6]=(short)yl; e8f[7]=(short)zl;
        short8 Av; if (half) Av = e8f; else Av = e07;
        if (q == 0) A0 = Av; else A1 = Av;
    }

    f32x16 m0, m1, zz;
#pragma unroll
    for (int i = 0; i < 16; ++i) { m0[i] = 3.402823466e38f; m1[i] = 3.402823466e38f; zz[i] = 0.0f; }

    for (int c = 0; c < QTILE / CHUNK; ++c) {
        __syncthreads();                          // previous phase fully consumed
        const float* bp = pts + ((size_t)(pj * N + b0 + c * CHUNK)) * 3;
#pragma unroll
        for (int k = 0; k < CHUNK / BLK; ++k) {   // 4 b-points per thread
            int i = k * BLK + tid;
            unsigned short xh, xl, yh, yl, zh, zl, sh, sl;
            xform_split(Pj, bp[i*3], bp[i*3+1], bp[i*3+2],
                        xh, xl, yh, yl, zh, zl, sh, sl);
            // -2 * bf16 piece is exact (power-of-two scale)
            short bxh=(short)f2bf(-2.0f*bf2f(xh)), byh=(short)f2bf(-2.0f*bf2f(yh)),
                  bzh=(short)f2bf(-2.0f*bf2f(zh));
            short bxl=(short)f2bf(-2.0f*bf2f(xl)), byl=(short)f2bf(-2.0f*bf2f(yl)),
                  bzl=(short)f2bf(-2.0f*bf2f(zl));
            short8 hi8, lo8;
            hi8[0]=bxh; hi8[1]=byh; hi8[2]=bzh; hi8[3]=bxl;
            hi8[4]=byl; hi8[5]=bzl; hi8[6]=bxh; hi8[7]=byh;
            lo8[0]=bzh; lo8[1]=one; lo8[2]=one; lo8[3]=(short)sh;
            lo8[4]=(short)sl; lo8[5]=bxl; lo8[6]=byl; lo8[7]=bzl;
            sbuf[i] = hi8; sbuf[CHUNK + i] = lo8;
        }
        __syncthreads();

        const short8* bsel = half ? (sbuf + CHUNK) : sbuf;
        for (int t = 0; t < CHUNK / 32; t += 2) { // 2 b-tiles per iteration
            short8 B0 = bsel[t * 32 + col];
            short8 B1 = bsel[(t + 1) * 32 + col];
            f32x16 d0 = __builtin_amdgcn_mfma_f32_32x32x16_bf16(A0, B0, zz, 0, 0, 0);
            f32x16 d1 = __builtin_amdgcn_mfma_f32_32x32x16_bf16(A0, B1, zz, 0, 0, 0);
#pragma unroll
            for (int i = 0; i < 16; ++i)          // fminf only -> v_min3 fusion
                m0[i] = fminf(m0[i], fminf(d0[i], d1[i]));
            d0 = __builtin_amdgcn_mfma_f32_32x32x16_bf16(A1, B0, zz, 0, 0, 0);
            d1 = __builtin_amdgcn_mfma_f32_32x32x16_bf16(A1, B1, zz, 0, 0, 0);
#pragma unroll
            for (int i = 0; i < 16; ++i)
                m1[i] = fminf(m1[i], fminf(d0[i], d1[i]));
        }
    }

    // ---- epilogue: butterfly min across the 32 lanes of each half ----
#pragma unroll
    for (int off = 1; off <= 16; off <<= 1) {
#pragma unroll
        for (int i = 0; i < 16; ++i) {
            m0[i] = fminf(m0[i], __shfl_xor(m0[i], off, 64));
            m1[i] = fminf(m1[i], __shfl_xor(m1[i], off, 64));
        }
    }
    if (col == 0) {
        // plain stores: per-x-block slot, no init, no atomics
        float* fm = minbuf + ((size_t)(p * 4 + blockIdx.x)) * N + abase;
#pragma unroll
        for (int r = 0; r < 16; ++r) {
            int row = (r & 3) + 8 * (r >> 2) + 4 * half;   // verified C/D mapping
            fm[row]      = fmaxf(m0[r], 0.0f);
            fm[32 + row] = fmaxf(m1[r], 0.0f);
        }
    }
}

// Kernel 2 (of 2): row d^2 = min over the 4 x-block slots; d = sqrt;
// block-reduce; scaled atomicAdd into scalar out (zeroed by chamfer).
__global__ void finalize_kernel(const float* __restrict__ minbuf,
                                float* __restrict__ out, float scale, int N) {
    __shared__ float red[BLK / 64];
    int idx = blockIdx.x * blockDim.x + threadIdx.x;   // 0 .. 6*N-1
    int p   = idx / N;
    int row = idx - p * N;
    const float* fm = minbuf + ((size_t)p * 4) * N + row;
    float d2 = fminf(fminf(fm[0], fm[(size_t)N]),
                     fminf(fm[(size_t)2 * N], fm[(size_t)3 * N]));
    float d = sqrtf(d2);
#pragma unroll
    for (int off = 32; off >= 1; off >>= 1)
        d += __shfl_down(d, off, 64);
    int lane = threadIdx.x & 63;
    int wid  = threadIdx.x >> 6;
    if (lane == 0) red[wid] = d;
    __syncthreads();
    if (threadIdx.x == 0) {
        float s = 0.0f;
#pragma unroll
        for (int wv = 0; wv < BLK / 64; ++wv) s += red[wv];
        atomicAdd(out, s * scale);
    }
}

extern "C" void kernel_launch(void* const* d_in, const int* in_sizes, int n_in,
                              void* d_out, int out_size, void* d_ws, size_t ws_size,
                              hipStream_t stream) {
    const float* points = (const float*)d_in[0];   // V x N x 3 fp32
    const float* poses  = (const float*)d_in[1];   // V x 4 x 4 fp32
    float* out = (float*)d_out;                    // scalar fp32

    const int N = in_sizes[0] / (VNUM * 3);        // 8192

    // ws: minbuf float[6][4][N] = 786 KB (plain stores, no init needed)
    float* minbuf = (float*)d_ws;

    dim3 grid(N / QTILE, N / 256, NPAIRS);         // 4 x 32 x 6 = 768 blocks
    chamfer_kernel<<<grid, BLK, 0, stream>>>(points, poses, minbuf, out, N);

    finalize_kernel<<<(NPAIRS * N) / BLK, BLK, 0, stream>>>(
        minbuf, out, 1.0f / (6.0f * (float)N), N);
}

// Round 23
// 28.963 us; speedup vs baseline: 1.7232x; 1.0050x over previous
//
#include <hip/hip_runtime.h>
#include <math.h>

// V=4 views, N=8192 points, 6 directed chamfer terms (pair p rows=view pi, min over view pj)
#define VNUM   4
#define NPAIRS 6
#define BLK    256
#define QTILE  2048   // b-points per block (quarter of N)
#define CHUNK  1024   // b-points staged per LDS phase (32 KB)

using short8  = __attribute__((ext_vector_type(8)))  short;
using f32x16  = __attribute__((ext_vector_type(16))) float;

__device__ inline unsigned short f2bf(float x) {           // RNE to bf16
    unsigned u = __float_as_uint(x);
    return (unsigned short)((u + 0x7FFFu + ((u >> 16) & 1u)) >> 16);
}
__device__ inline float bf2f(unsigned short b) {
    return __uint_as_float(((unsigned)b) << 16);
}

// world-transform + hi/lo bf16 split (s = |p|^2) -- verified in R7/R21
__device__ inline void xform_split_v(const float* __restrict__ P,
                                     float px, float py, float pz,
                                     unsigned short& xh, unsigned short& xl,
                                     unsigned short& yh, unsigned short& yl,
                                     unsigned short& zh, unsigned short& zl,
                                     unsigned short& sh, unsigned short& sl) {
    float x = fmaf(P[0], px, fmaf(P[1], py, fmaf(P[2],  pz, P[3])));
    float y = fmaf(P[4], px, fmaf(P[5], py, fmaf(P[6],  pz, P[7])));
    float z = fmaf(P[8], px, fmaf(P[9], py, fmaf(P[10], pz, P[11])));
    float s = fmaf(x, x, fmaf(y, y, z * z));
    xh = f2bf(x); xl = f2bf(x - bf2f(xh));
    yh = f2bf(y); yl = f2bf(y - bf2f(yh));
    zh = f2bf(z); zl = f2bf(z - bf2f(zh));
    sh = f2bf(s); sl = f2bf(s - bf2f(sh));
}

// Kernel 1 (of 2): fused fragment-build + chamfer (R21 champion), ONE change:
// __launch_bounds__(BLK,3) -- grid is exactly 3 blocks/CU, so the ",4" cap
// bought nothing while constraining the allocator to 128 VGPRs with the
// fused B-transform's extra live state. Cap ~170 removes any silent
// spill/throttle risk (R8/R14/R15 lesson).
__global__ __launch_bounds__(BLK, 3)
void chamfer_kernel(const float* __restrict__ pts,
                    const float* __restrict__ poses,
                    float* __restrict__ minbuf,
                    float* __restrict__ out, int N) {
    __shared__ short8 sbuf[CHUNK * 2];            // 32 KB: [hi x1024][lo x1024]
    const int p  = blockIdx.z;
    const int pi = (p < 3) ? 0 : ((p < 5) ? 1 : 2);
    const int pj = (p < 3) ? (p + 1) : ((p < 5) ? (p - 1) : 3);
    const int tid  = threadIdx.x;
    const int w    = tid >> 6;
    const int l    = tid & 63;
    const int col  = l & 31;
    const int half = l >> 5;

    const int abase = (blockIdx.y * 4 + w) * 64;  // 64 a-rows per wave
    const int b0    = blockIdx.x * QTILE;
    const float* Pi = poses + pi * 16;
    const float* Pj = poses + pj * 16;
    const short one = (short)0x3F80;

    if (blockIdx.x == 0 && blockIdx.y == 0 && p == 0 && tid == 0)
        *out = 0.0f;                              // finalize runs strictly after

    // ---- A-fragments for this lane's two a-points (R7/R21-verified) ----
    short8 A0, A1;
#pragma unroll
    for (int q = 0; q < 2; ++q) {
        int r = pi * N + abase + col + q * 32;
        unsigned short xh, xl, yh, yl, zh, zl, sh, sl;
        xform_split_v(Pi, pts[r*3], pts[r*3+1], pts[r*3+2],
                      xh, xl, yh, yl, zh, zl, sh, sl);
        short8 e07, e8f;
        e07[0]=(short)xh; e07[1]=(short)yh; e07[2]=(short)zh; e07[3]=(short)xh;
        e07[4]=(short)yh; e07[5]=(short)zh; e07[6]=(short)xl; e07[7]=(short)yl;
        e8f[0]=(short)zl; e8f[1]=(short)sh; e8f[2]=(short)sl; e8f[3]=one;
        e8f[4]=one;       e8f[5]=(short)xl; e8f[6]=(short)yl; e8f[7]=(short)zl;
        short8 Av; if (half) Av = e8f; else Av = e07;
        if (q == 0) A0 = Av; else A1 = Av;
    }

    f32x16 m0, m1, zz;
#pragma unroll
    for (int i = 0; i < 16; ++i) { m0[i] = 3.402823466e38f; m1[i] = 3.402823466e38f; zz[i] = 0.0f; }

    for (int c = 0; c < QTILE / CHUNK; ++c) {
        __syncthreads();                          // previous phase fully consumed
        const float* bp = pts + ((size_t)(pj * N + b0 + c * CHUNK)) * 3;
#pragma unroll
        for (int k = 0; k < CHUNK / BLK; ++k) {   // 4 b-points per thread
            int i = k * BLK + tid;
            unsigned short xh, xl, yh, yl, zh, zl, sh, sl;
            xform_split_v(Pj, bp[i*3], bp[i*3+1], bp[i*3+2],
                          xh, xl, yh, yl, zh, zl, sh, sl);
            // -2 * bf16 piece is exact (power-of-two scale)
            short bxh=(short)f2bf(-2.0f*bf2f(xh)), byh=(short)f2bf(-2.0f*bf2f(yh)),
                  bzh=(short)f2bf(-2.0f*bf2f(zh));
            short bxl=(short)f2bf(-2.0f*bf2f(xl)), byl=(short)f2bf(-2.0f*bf2f(yl)),
                  bzl=(short)f2bf(-2.0f*bf2f(zl));
            short8 hi8, lo8;
            hi8[0]=bxh; hi8[1]=byh; hi8[2]=bzh; hi8[3]=bxl;
            hi8[4]=byl; hi8[5]=bzl; hi8[6]=bxh; hi8[7]=byh;
            lo8[0]=bzh; lo8[1]=one; lo8[2]=one; lo8[3]=(short)sh;
            lo8[4]=(short)sl; lo8[5]=bxl; lo8[6]=byl; lo8[7]=bzl;
            sbuf[i] = hi8; sbuf[CHUNK + i] = lo8;
        }
        __syncthreads();

        const short8* bsel = half ? (sbuf + CHUNK) : sbuf;
        for (int t = 0; t < CHUNK / 32; t += 2) { // 2 b-tiles per iteration
            short8 B0 = bsel[t * 32 + col];
            short8 B1 = bsel[(t + 1) * 32 + col];
            f32x16 d0 = __builtin_amdgcn_mfma_f32_32x32x16_bf16(A0, B0, zz, 0, 0, 0);
            f32x16 d1 = __builtin_amdgcn_mfma_f32_32x32x16_bf16(A0, B1, zz, 0, 0, 0);
#pragma unroll
            for (int i = 0; i < 16; ++i)          // fminf only -> v_min3 fusion
                m0[i] = fminf(m0[i], fminf(d0[i], d1[i]));
            d0 = __builtin_amdgcn_mfma_f32_32x32x16_bf16(A1, B0, zz, 0, 0, 0);
            d1 = __builtin_amdgcn_mfma_f32_32x32x16_bf16(A1, B1, zz, 0, 0, 0);
#pragma unroll
            for (int i = 0; i < 16; ++i)
                m1[i] = fminf(m1[i], fminf(d0[i], d1[i]));
        }
    }

    // ---- epilogue: butterfly min across the 32 lanes of each half ----
#pragma unroll
    for (int off = 1; off <= 16; off <<= 1) {
#pragma unroll
        for (int i = 0; i < 16; ++i) {
            m0[i] = fminf(m0[i], __shfl_xor(m0[i], off, 64));
            m1[i] = fminf(m1[i], __shfl_xor(m1[i], off, 64));
        }
    }
    if (col == 0) {
        // plain stores: per-x-block slot, no init, no atomics
        float* fm = minbuf + ((size_t)(p * 4 + blockIdx.x)) * N + abase;
#pragma unroll
        for (int r = 0; r < 16; ++r) {
            int row = (r & 3) + 8 * (r >> 2) + 4 * half;   // verified C/D mapping
            fm[row]      = fmaxf(m0[r], 0.0f);
            fm[32 + row] = fmaxf(m1[r], 0.0f);
        }
    }
}

// Kernel 2 (of 2): row d^2 = min over the 4 x-block slots; d = sqrt;
// block-reduce; scaled atomicAdd into scalar out (zeroed by chamfer).
__global__ void finalize_kernel(const float* __restrict__ minbuf,
                                float* __restrict__ out, float scale, int N) {
    __shared__ float red[BLK / 64];
    int idx = blockIdx.x * blockDim.x + threadIdx.x;   // 0 .. 6*N-1
    int p   = idx / N;
    int row = idx - p * N;
    const float* fm = minbuf + ((size_t)p * 4) * N + row;
    float d2 = fminf(fminf(fm[0], fm[(size_t)N]),
                     fminf(fm[(size_t)2 * N], fm[(size_t)3 * N]));
    float d = sqrtf(d2);
#pragma unroll
    for (int off = 32; off >= 1; off >>= 1)
        d += __shfl_down(d, off, 64);
    int lane = threadIdx.x & 63;
    int wid  = threadIdx.x >> 6;
    if (lane == 0) red[wid] = d;
    __syncthreads();
    if (threadIdx.x == 0) {
        float s = 0.0f;
#pragma unroll
        for (int wv = 0; wv < BLK / 64; ++wv) s += red[wv];
        atomicAdd(out, s * scale);
    }
}

extern "C" void kernel_launch(void* const* d_in, const int* in_sizes, int n_in,
                              void* d_out, int out_size, void* d_ws, size_t ws_size,
                              hipStream_t stream) {
    const float* points = (const float*)d_in[0];   // V x N x 3 fp32
    const float* poses  = (const float*)d_in[1];   // V x 4 x 4 fp32
    float* out = (float*)d_out;                    // scalar fp32

    const int N = in_sizes[0] / (VNUM * 3);        // 8192

    // ws: minbuf float[6][4][N] = 786 KB (plain stores, no init needed)
    float* minbuf = (float*)d_ws;

    dim3 grid(N / QTILE, N / 256, NPAIRS);         // 4 x 32 x 6 = 768 blocks
    chamfer_kernel<<<grid, BLK, 0, stream>>>(points, poses, minbuf, out, N);

    finalize_kernel<<<(NPAIRS * N) / BLK, BLK, 0, stream>>>(
        minbuf, out, 1.0f / (6.0f * (float)N), N);
}